// Round 3
// baseline (513.475 us; speedup 1.0000x reference)
//
#include <hip/hip_runtime.h>
#include <math.h>

#define NN 50000
#define NE 800000
#define IND 256
#define HD 64

// ---------------------------------------------------------------------------
// Kernel 1: h = tanh(node_x @ proj_w + proj_b)   [NN, 64]
// One node per thread; x row streamed as float4; proj_w rows are wave-uniform
// -> scalar loads. 64 fp32 accumulators per thread.
// ---------------------------------------------------------------------------
__global__ __launch_bounds__(256) void k_proj(
    const float* __restrict__ x, const float* __restrict__ pw,
    const float* __restrict__ pbias, float* __restrict__ h) {
  int n = blockIdx.x * 256 + threadIdx.x;
  if (n >= NN) return;
  float acc[HD];
#pragma unroll
  for (int i = 0; i < HD / 4; ++i) {
    float4 b = *(const float4*)(pbias + 4 * i);
    acc[4 * i + 0] = b.x; acc[4 * i + 1] = b.y;
    acc[4 * i + 2] = b.z; acc[4 * i + 3] = b.w;
  }
  const float4* xr = (const float4*)(x + (size_t)n * IND);
  for (int kc = 0; kc < IND / 4; ++kc) {
    float4 xv = xr[kc];
    float xs[4] = {xv.x, xv.y, xv.z, xv.w};
#pragma unroll
    for (int kk = 0; kk < 4; ++kk) {
      const float4* wr = (const float4*)(pw + (size_t)(4 * kc + kk) * HD);
#pragma unroll
      for (int i = 0; i < HD / 4; ++i) {
        float4 w = wr[i];
        acc[4 * i + 0] = fmaf(xs[kk], w.x, acc[4 * i + 0]);
        acc[4 * i + 1] = fmaf(xs[kk], w.y, acc[4 * i + 1]);
        acc[4 * i + 2] = fmaf(xs[kk], w.z, acc[4 * i + 2]);
        acc[4 * i + 3] = fmaf(xs[kk], w.w, acc[4 * i + 3]);
      }
    }
  }
  float4* hr = (float4*)(h + (size_t)n * HD);
#pragma unroll
  for (int i = 0; i < HD / 4; ++i) {
    hr[i] = make_float4(tanhf(acc[4 * i + 0]), tanhf(acc[4 * i + 1]),
                        tanhf(acc[4 * i + 2]), tanhf(acc[4 * i + 3]));
  }
}

// ---------------------------------------------------------------------------
// Kernel 2: per-node precompute of the LINEAR half of the edge MLP:
//   Pa = h @ w1[0:64,:]   (z_u block)
//   Pb = h @ w1[64:128,:] (z_v block)
// Moves 2 of the 4 [64,64] matvecs from per-EDGE (800k) to per-NODE (50k).
// ---------------------------------------------------------------------------
__global__ __launch_bounds__(256) void k_pab(
    const float* __restrict__ h, const float* __restrict__ w1,
    float* __restrict__ pa, float* __restrict__ pb) {
  int n = blockIdx.x * 256 + threadIdx.x;
  if (n >= NN) return;
  float accA[HD], accB[HD];
#pragma unroll
  for (int i = 0; i < HD; ++i) { accA[i] = 0.f; accB[i] = 0.f; }
  const float* hrow = h + (size_t)n * HD;
  for (int c = 0; c < 4; ++c) {
    float hc[16];
#pragma unroll
    for (int t = 0; t < 4; ++t)
      *(float4*)&hc[4 * t] = *(const float4*)(hrow + 16 * c + 4 * t);
#pragma unroll
    for (int j = 0; j < 16; ++j) {
      float z = hc[j];
      const float4* wa = (const float4*)(w1 + (size_t)(16 * c + j) * HD);
      const float4* wb = (const float4*)(w1 + (size_t)(HD + 16 * c + j) * HD);
#pragma unroll
      for (int i = 0; i < HD / 4; ++i) {
        float4 a = wa[i]; float4 b = wb[i];
        accA[4 * i + 0] = fmaf(z, a.x, accA[4 * i + 0]);
        accA[4 * i + 1] = fmaf(z, a.y, accA[4 * i + 1]);
        accA[4 * i + 2] = fmaf(z, a.z, accA[4 * i + 2]);
        accA[4 * i + 3] = fmaf(z, a.w, accA[4 * i + 3]);
        accB[4 * i + 0] = fmaf(z, b.x, accB[4 * i + 0]);
        accB[4 * i + 1] = fmaf(z, b.y, accB[4 * i + 1]);
        accB[4 * i + 2] = fmaf(z, b.z, accB[4 * i + 2]);
        accB[4 * i + 3] = fmaf(z, b.w, accB[4 * i + 3]);
      }
    }
  }
  float4* par = (float4*)(pa + (size_t)n * HD);
  float4* pbr = (float4*)(pb + (size_t)n * HD);
#pragma unroll
  for (int i = 0; i < HD / 4; ++i) {
    par[i] = make_float4(accA[4 * i], accA[4 * i + 1], accA[4 * i + 2], accA[4 * i + 3]);
    pbr[i] = make_float4(accB[4 * i], accB[4 * i + 1], accB[4 * i + 2], accB[4 * i + 3]);
  }
}

// ---------------------------------------------------------------------------
// Kernel 3: per-edge fused MLP + evidential head. One edge per thread.
//   hidden = relu(Pa[u] + Pb[v] + |z_u-z_v| @ Wc + (z_u*z_v) @ Wd + b1)
//   logits = hidden @ w2 + b2 ; softplus head; 4 outputs.
// ---------------------------------------------------------------------------
__global__ __launch_bounds__(256) void k_edge(
    const int* __restrict__ eu, const int* __restrict__ evi,
    const float* __restrict__ h, const float* __restrict__ pa,
    const float* __restrict__ pb, const float* __restrict__ w1,
    const float* __restrict__ b1, const float* __restrict__ w2,
    const float* __restrict__ b2, float* __restrict__ out) {
  int e = blockIdx.x * 256 + threadIdx.x;
  if (e >= NE) return;
  int u = eu[e], v = evi[e];

  const float* pau = pa + (size_t)u * HD;
  const float* pbv = pb + (size_t)v * HD;
  float acc[HD];
#pragma unroll
  for (int i = 0; i < HD / 4; ++i) {
    float4 A = *(const float4*)(pau + 4 * i);
    float4 B = *(const float4*)(pbv + 4 * i);
    float4 bb = *(const float4*)(b1 + 4 * i);
    acc[4 * i + 0] = A.x + B.x + bb.x;
    acc[4 * i + 1] = A.y + B.y + bb.y;
    acc[4 * i + 2] = A.z + B.z + bb.z;
    acc[4 * i + 3] = A.w + B.w + bb.w;
  }

  const float* hu = h + (size_t)u * HD;
  const float* hv = h + (size_t)v * HD;
  for (int c = 0; c < 4; ++c) {
    float cu[16], cv[16];
#pragma unroll
    for (int t = 0; t < 4; ++t) {
      *(float4*)&cu[4 * t] = *(const float4*)(hu + 16 * c + 4 * t);
      *(float4*)&cv[4 * t] = *(const float4*)(hv + 16 * c + 4 * t);
    }
#pragma unroll
    for (int j = 0; j < 16; ++j) {
      float zu = cu[j], zv = cv[j];
      float a = fabsf(zu - zv);
      float m = zu * zv;
      const float4* wc = (const float4*)(w1 + (size_t)(2 * HD + 16 * c + j) * HD);
      const float4* wd = (const float4*)(w1 + (size_t)(3 * HD + 16 * c + j) * HD);
#pragma unroll
      for (int i = 0; i < HD / 4; ++i) {
        float4 C = wc[i]; float4 D = wd[i];
        acc[4 * i + 0] = fmaf(a, C.x, fmaf(m, D.x, acc[4 * i + 0]));
        acc[4 * i + 1] = fmaf(a, C.y, fmaf(m, D.y, acc[4 * i + 1]));
        acc[4 * i + 2] = fmaf(a, C.z, fmaf(m, D.z, acc[4 * i + 2]));
        acc[4 * i + 3] = fmaf(a, C.w, fmaf(m, D.w, acc[4 * i + 3]));
      }
    }
  }

  // layer 2: [64] -> [2]; w2 is [64,2] row-major, uniform scalar loads
  float l0 = b2[0], l1 = b2[1];
#pragma unroll
  for (int i = 0; i < HD; ++i) {
    float r = fmaxf(acc[i], 0.f);
    l0 = fmaf(r, w2[2 * i + 0], l0);
    l1 = fmaf(r, w2[2 * i + 1], l1);
  }

  // softplus = max(x,0) + log1p(exp(-|x|))  (matches jax.nn.softplus)
  float ev0 = fmaxf(l0, 0.f) + log1pf(expf(-fabsf(l0)));
  float ev1 = fmaxf(l1, 0.f) + log1pf(expf(-fabsf(l1)));
  float a0 = ev0 + 1.f, a1 = ev1 + 1.f;
  float S = a0 + a1;
  float unc = 2.f / (S + 1e-12f);
  float p0 = a0 / S, p1 = a1 / S;

  // outputs concatenated flat: evidence[E,2] | alpha[E,2] | uncertainty[E] | probs[E,2]
  ((float2*)out)[e] = make_float2(ev0, ev1);
  ((float2*)(out + 2 * (size_t)NE))[e] = make_float2(a0, a1);
  (out + 4 * (size_t)NE)[e] = unc;
  ((float2*)(out + 5 * (size_t)NE))[e] = make_float2(p0, p1);
}

// ---------------------------------------------------------------------------
extern "C" void kernel_launch(void* const* d_in, const int* in_sizes, int n_in,
                              void* d_out, int out_size, void* d_ws, size_t ws_size,
                              hipStream_t stream) {
  const int* ei      = (const int*)d_in[0];    // [2, E] int32
  const float* x     = (const float*)d_in[1];  // [NN, 256]
  const float* pw    = (const float*)d_in[2];  // [256, 64]
  const float* pbias = (const float*)d_in[3];  // [64]
  const float* w1    = (const float*)d_in[4];  // [256, 64]
  const float* b1    = (const float*)d_in[5];  // [64]
  const float* w2    = (const float*)d_in[6];  // [64, 2]
  const float* b2    = (const float*)d_in[7];  // [2]
  float* out = (float*)d_out;

  // ws layout: h [NN,64] | Pa [NN,64] | Pb [NN,64]  = 38.4 MB total
  float* h  = (float*)d_ws;
  float* pa = h + (size_t)NN * HD;
  float* pb = pa + (size_t)NN * HD;

  k_proj<<<(NN + 255) / 256, 256, 0, stream>>>(x, pw, pbias, h);
  k_pab<<<(NN + 255) / 256, 256, 0, stream>>>(h, w1, pa, pb);
  k_edge<<<(NE + 255) / 256, 256, 0, stream>>>(ei, ei + NE, h, pa, pb,
                                               w1, b1, w2, b2, out);
}